// Round 12
// baseline (22186.304 us; speedup 1.0000x reference)
//
#include <hip/hip_runtime.h>
#include <hip/hip_bf16.h>

typedef __attribute__((ext_vector_type(8))) short short8;
typedef __attribute__((ext_vector_type(4))) float f32x4;

#define HID 512
#define T_STEPS 90
#define RBLK 128
#define NBLK 128  /* 16384 rows / 128 */

__device__ __forceinline__ unsigned short f2bf(float x) {
  unsigned int u = __float_as_uint(x);
  u = u + 0x7FFFu + ((u >> 16) & 1u);   // round-to-nearest-even
  return (unsigned short)(u >> 16);
}
__device__ __forceinline__ float bf2f(unsigned short s) {
  return __uint_as_float(((unsigned int)s) << 16);
}

// branch-free exact-erf gelu (A&S 7.1.26, |err_erf| <= 1.5e-7)
__device__ __forceinline__ float gelu_f(float x) {
  float u = fabsf(x) * 0.70710678118654752f;
  float d = fmaf(0.3275911f, u, 1.0f);
  float t; asm("v_rcp_f32 %0, %1" : "=v"(t) : "v"(d));
  float poly = t * (0.254829592f + t * (-0.284496736f + t * (1.421413741f +
               t * (-1.453152027f + t * 1.061405429f))));
  float m = -u * u * 1.44269504088896f;
  float ex; asm("v_exp_f32 %0, %1" : "=v"(ex) : "v"(m));
  float e = 1.0f - poly * ex;       // erf(|x|/sqrt2)
  e = copysignf(e, x);
  return 0.5f * x * (1.0f + e);
}

// ---- prep: fp32 W1/W2 -> bf16 row-major in workspace ----
__global__ void prep_convert(const float* __restrict__ W1, const float* __restrict__ W2,
                             unsigned short* __restrict__ wbf) {
  int i = blockIdx.x * blockDim.x + threadIdx.x;
  if (i >= 524288) return;
  float v = (i < 262144) ? W1[i] : W2[i - 262144];
  wbf[i] = f2bf(v);
}

// ---- prep: Wout -> bf16 B-fragment order (slot s = kk*64 + lane) ----
__global__ void prep_wout(const float* __restrict__ Wout, unsigned short* __restrict__ dst) {
  int s = blockIdx.x * blockDim.x + threadIdx.x;
  if (s >= 1024) return;
  int c = s >> 6, l = s & 63;
  int col = l & 15;
  int h0 = c * 32 + (l >> 4) * 8;
  const float* p = Wout + (size_t)col * HID + h0;
  unsigned short* q = dst + (size_t)s * 8;
#pragma unroll
  for (int e = 0; e < 8; ++e) q[e] = f2bf(p[e]);
}

// corr[t][o] = bout[o] - sum_h pos[t+1][h] * bf16(Wout[o][h])   (t<89; corr[89][o]=bout[o])
__global__ void prep_corr(const float* __restrict__ pos, const float* __restrict__ bout,
                          const float* __restrict__ Wout, float* __restrict__ corr) {
  int i = blockIdx.x * blockDim.x + threadIdx.x;
  if (i >= T_STEPS * 16) return;
  int t = i >> 4, o = i & 15;
  float s = 0.f;
  if (t < T_STEPS - 1) {
    const float* pe = pos + (t + 1) * HID;
    for (int h = 0; h < HID; ++h) s += pe[h] * bf2f(f2bf(Wout[o * HID + h]));
  }
  corr[i] = bout[o] - s;
}

__global__ __launch_bounds__(512, 2) void fd_main(
    const float* __restrict__ latent, const float* __restrict__ b1,
    const float* __restrict__ b2, const float* __restrict__ pos,
    const unsigned short* __restrict__ W1bf, const unsigned short* __restrict__ W2bf,
    const unsigned short* __restrict__ Woutf, const float* __restrict__ corr,
    unsigned int* __restrict__ gbar, float* __restrict__ out) {
  __shared__ __align__(16) unsigned short Xs[RBLK * HID];   // 128KB, X_t bf16 (swizzled)
  __shared__ __align__(16) unsigned short Hq[RBLK * 128];   // 32KB, h col-phase (swizzled)
  const int tid = threadIdx.x;
  const int w = tid >> 6;
  const int l = tid & 63;
  const int lh = l & 15, lq = l >> 4;
  const int cb = w << 6;        // this wave's 64-col slice of state/GEMM2 output
  const int cbl = cb + lh;
  const int bid = blockIdx.x;
  const int rowBase = bid * RBLK;

  // biases: GEMM1 col (phase p) = p*128 + w*16 + lh; GEMM2 col = cb + nt*16 + lh
  float b1v[4], b2v[4];
#pragma unroll
  for (int p = 0; p < 4; ++p) b1v[p] = b1[p * 128 + w * 16 + lh];
#pragma unroll
  for (int nt = 0; nt < 4; ++nt) b2v[nt] = b2[cbl + nt * 16];

  // state in regs, MFMA C-layout: st[mt][nt][r] = state[mt*16+lq*4+r][cb+nt*16+lh]
  f32x4 st[8][4];
#pragma unroll
  for (int mt = 0; mt < 8; ++mt)
#pragma unroll
    for (int nt = 0; nt < 4; ++nt)
#pragma unroll
      for (int r = 0; r < 4; ++r)
        st[mt][nt][r] = latent[(size_t)(rowBase + mt * 16 + lq * 4 + r) * HID + cbl + nt * 16];

  // write X_0 = state + pe[0]
  {
#pragma unroll
    for (int nt = 0; nt < 4; ++nt) {
      float pev = pos[cbl + nt * 16];
#pragma unroll
      for (int mt = 0; mt < 8; ++mt)
#pragma unroll
        for (int r = 0; r < 4; ++r) {
          int row = mt * 16 + lq * 4 + r;
          int idx = ((row << 9) + cbl + nt * 16) ^ ((row & 7) << 3);
          Xs[idx] = f2bf(st[mt][nt][r] + pev);
        }
    }
  }
  __syncthreads();

  for (int t = 0; t < T_STEPS; ++t) {
    // st += b2 once per step (before partial-K accumulation)
#pragma unroll
    for (int mt = 0; mt < 8; ++mt)
#pragma unroll
      for (int nt = 0; nt < 4; ++nt)
        st[mt][nt] += b2v[nt];

#pragma unroll
    for (int p = 0; p < 4; ++p) {
      // ---- GEMM1 phase: a1[rows 0..127][col p*128+w*16+lh], K=512 ----
      f32x4 a1[8];
#pragma unroll
      for (int mt = 0; mt < 8; ++mt)
        a1[mt] = (f32x4){b1v[p], b1v[p], b1v[p], b1v[p]};
      {
        const unsigned short* wrow = W1bf + (size_t)(p * 128 + w * 16 + lh) * HID + lq * 8;
        short8 pre[4];
#pragma unroll
        for (int d = 0; d < 3; ++d) pre[d] = *(const short8*)(wrow + d * 32);
#pragma unroll
        for (int c = 0; c < 16; ++c) {
          if (c + 3 < 16) pre[(c + 3) & 3] = *(const short8*)(wrow + (c + 3) * 32);
          short8 af[8];
#pragma unroll
          for (int mt = 0; mt < 8; ++mt) {
            int row = mt * 16 + lh;
            af[mt] = *(const short8*)(Xs + (((row << 9) + c * 32 + lq * 8) ^ ((row & 7) << 3)));
          }
#pragma unroll
          for (int mt = 0; mt < 8; ++mt)
            a1[mt] = __builtin_amdgcn_mfma_f32_16x16x32_bf16(af[mt], pre[c & 3], a1[mt], 0, 0, 0);
        }
      }
      // gelu -> Hq (phase-local k = w*16+lh)
#pragma unroll
      for (int mt = 0; mt < 8; ++mt)
#pragma unroll
        for (int r = 0; r < 4; ++r) {
          int row = mt * 16 + lq * 4 + r;
          int idx = ((row << 7) + w * 16 + lh) ^ ((row & 7) << 3);
          Hq[idx] = f2bf(gelu_f(a1[mt][r]));
        }
      __syncthreads();

      // ---- GEMM2 partial: st[][cb..] += Hq(K=128 slice) * W2^T ----
      {
        const unsigned short* w2r0 = W2bf + (size_t)(cb + 0 * 16 + lh) * HID + p * 128 + lq * 8;
        const unsigned short* w2r1 = W2bf + (size_t)(cb + 1 * 16 + lh) * HID + p * 128 + lq * 8;
        const unsigned short* w2r2 = W2bf + (size_t)(cb + 2 * 16 + lh) * HID + p * 128 + lq * 8;
        const unsigned short* w2r3 = W2bf + (size_t)(cb + 3 * 16 + lh) * HID + p * 128 + lq * 8;
        short8 pre2[2][4];
        pre2[0][0] = *(const short8*)w2r0; pre2[0][1] = *(const short8*)w2r1;
        pre2[0][2] = *(const short8*)w2r2; pre2[0][3] = *(const short8*)w2r3;
#pragma unroll
        for (int c2 = 0; c2 < 4; ++c2) {
          if (c2 + 1 < 4) {
            const int s = (c2 + 1) & 1;
            pre2[s][0] = *(const short8*)(w2r0 + (c2 + 1) * 32);
            pre2[s][1] = *(const short8*)(w2r1 + (c2 + 1) * 32);
            pre2[s][2] = *(const short8*)(w2r2 + (c2 + 1) * 32);
            pre2[s][3] = *(const short8*)(w2r3 + (c2 + 1) * 32);
          }
          short8 af[8];
#pragma unroll
          for (int mt = 0; mt < 8; ++mt) {
            int row = mt * 16 + lh;
            af[mt] = *(const short8*)(Hq + (((row << 7) + c2 * 32 + lq * 8) ^ ((row & 7) << 3)));
          }
#pragma unroll
          for (int mt = 0; mt < 8; ++mt)
#pragma unroll
            for (int nt = 0; nt < 4; ++nt)
              st[mt][nt] = __builtin_amdgcn_mfma_f32_16x16x32_bf16(af[mt], pre2[c2 & 1][nt], st[mt][nt], 0, 0, 0);
        }
      }
      __syncthreads();   // Hq free for next phase
    }

    // ---- write X_{t+1} = state + pe[t+1]  (pe=0 for last step) ----
    {
#pragma unroll
      for (int nt = 0; nt < 4; ++nt) {
        float pev = (t < T_STEPS - 1) ? pos[(t + 1) * HID + cbl + nt * 16] : 0.f;
#pragma unroll
        for (int mt = 0; mt < 8; ++mt)
#pragma unroll
          for (int r = 0; r < 4; ++r) {
            int row = mt * 16 + lq * 4 + r;
            int idx = ((row << 9) + cbl + nt * 16) ^ ((row & 7) << 3);
            Xs[idx] = f2bf(st[mt][nt][r] + pev);
          }
      }
    }
    __syncthreads();

    // ---- out-proj (waves 0-3, 2 m-tiles each) + global phase-lock (wave 7) ----
    if (w < 4) {
      float cv = corr[t * 16 + lh];
#pragma unroll
      for (int h2 = 0; h2 < 2; ++h2) {
        const int mt = w * 2 + h2;
        f32x4 ao = {cv, cv, cv, cv};
        short8 po[4];
#pragma unroll
        for (int d = 0; d < 3; ++d) po[d] = *(const short8*)(Woutf + (size_t)(d * 64 + l) * 8);
#pragma unroll
        for (int kk = 0; kk < 16; ++kk) {
          if (kk + 3 < 16) po[(kk + 3) & 3] = *(const short8*)(Woutf + (size_t)((kk + 3) * 64 + l) * 8);
          int row = mt * 16 + lh;
          short8 af = *(const short8*)(Xs + (((row << 9) + kk * 32 + lq * 8) ^ ((row & 7) << 3)));
          ao = __builtin_amdgcn_mfma_f32_16x16x32_bf16(af, po[kk & 3], ao, 0, 0, 0);
        }
#pragma unroll
        for (int r = 0; r < 4; ++r) {
          int row = rowBase + mt * 16 + lq * 4 + r;
          int bb = row >> 8, ss = row & 255;
          out[(size_t)((bb * T_STEPS + t) * 256 + ss) * 16 + lh] = ao[r];
        }
      }
    } else if (tid == 448) {
      // Global alignment barrier: monotonic counter; purely a scheduling device
      // (no data crosses it) -- relaxed atomics + bounded spin, cannot deadlock.
      unsigned int target = (unsigned int)NBLK * (unsigned int)(t + 1);
      __hip_atomic_fetch_add(gbar, 1u, __ATOMIC_RELAXED, __HIP_MEMORY_SCOPE_AGENT);
      for (int p = 0; p < 2000; ++p) {
        unsigned int v = __hip_atomic_load(gbar, __ATOMIC_RELAXED, __HIP_MEMORY_SCOPE_AGENT);
        if (v >= target) break;
        __builtin_amdgcn_s_sleep(4);
      }
    }
    __syncthreads();
  }
}

extern "C" void kernel_launch(void* const* d_in, const int* in_sizes, int n_in,
                              void* d_out, int out_size, void* d_ws, size_t ws_size,
                              hipStream_t stream) {
  const float* latent = (const float*)d_in[0];
  const float* W1 = (const float*)d_in[1];
  const float* b1 = (const float*)d_in[2];
  const float* W2 = (const float*)d_in[3];
  const float* b2 = (const float*)d_in[4];
  const float* Wout = (const float*)d_in[5];
  const float* bout = (const float*)d_in[6];
  const float* pos = (const float*)d_in[7];

  unsigned short* wbf = (unsigned short*)d_ws;
  unsigned short* W1bf = wbf;                     // 512KB row-major bf16
  unsigned short* W2bf = wbf + 262144;            // 512KB
  unsigned short* Woutf = wbf + 524288;           // 16KB, B-frag order
  float* corr = (float*)(wbf + 532480);           // 90*16 floats
  unsigned int* gbar = (unsigned int*)((char*)d_ws + 1072128);

  hipMemsetAsync(gbar, 0, 64, stream);  // deterministic per launch/replay
  prep_convert<<<2048, 256, 0, stream>>>(W1, W2, wbf);
  prep_wout<<<4, 256, 0, stream>>>(Wout, Woutf);
  prep_corr<<<6, 256, 0, stream>>>(pos, bout, Wout, corr);
  fd_main<<<NBLK, 512, 0, stream>>>(latent, b1, b2, pos, W1bf, W2bf, Woutf, corr,
                                    gbar, (float*)d_out);
}